// Round 4
// baseline (410.518 us; speedup 1.0000x reference)
//
#include <hip/hip_runtime.h>
#include <cstdint>
#include <cstddef>

#define GLOBAL_AS __attribute__((address_space(1)))
#define LDS_AS __attribute__((address_space(3)))

typedef __attribute__((ext_vector_type(8))) short short8;
typedef __attribute__((ext_vector_type(4))) float floatx4;

#if defined(__has_builtin)
#if __has_builtin(__builtin_amdgcn_cvt_pk_fp8_f32) && __has_builtin(__builtin_amdgcn_cvt_f32_fp8)
#define HAVE_HW_FP8 1
#endif
#endif

static __device__ __forceinline__ unsigned short f2bf(float f) {
  uint32_t u = __builtin_bit_cast(uint32_t, f);
  u += 0x7fffu + ((u >> 16) & 1u);
  return (unsigned short)(u >> 16);
}

// OCP e4m3 encode (RNE, saturate to 448)
static __device__ __forceinline__ unsigned char f2fp8(float f) {
#ifdef HAVE_HW_FP8
  float c = fminf(fmaxf(f, -448.f), 448.f);
  return (unsigned char)(__builtin_amdgcn_cvt_pk_fp8_f32(c, 0.f, 0, false) & 0xff);
#else
  unsigned char s = 0;
  if (f < 0.f) { s = 0x80; f = -f; }
  if (f >= 448.f) return s | 0x7e;
  if (f < 0.015625f) {  // below 2^-6: subnormal, units of 2^-9 (linear codes 0..8)
    int r = (int)(f * 512.f + 0.5f);
    return s | (unsigned char)r;
  }
  uint32_t u = __builtin_bit_cast(uint32_t, f);
  int e = (int)((u >> 23) & 0xff) - 127;
  uint32_t keep = (u >> 20) & 7, rest = u & 0xfffffu;
  if (rest > 0x80000u || (rest == 0x80000u && (keep & 1))) ++keep;
  if (keep == 8) { keep = 0; ++e; }
  if (e > 8) return s | 0x7e;
  return s | (unsigned char)(((e + 7) << 3) | keep);
#endif
}
#ifndef HAVE_HW_FP8
static __device__ __forceinline__ float fp8tof(unsigned int b) {
  float sg = (b & 0x80) ? -1.f : 1.f;
  int e = (b >> 3) & 0xf, m = b & 7;
  if (e == 0) return sg * (float)m * 0.001953125f;
  return sg * (1.f + (float)m * 0.125f) * exp2f((float)(e - 7));
}
#endif

static __device__ __forceinline__ void wait_vm0() {
  // vmcnt(0), expcnt/lgkmcnt unconstrained: bits vm[3:0]=0, exp[6:4]=7, lgkm[11:8]=0xf
  __builtin_amdgcn_s_waitcnt(0x0f70);
}

// ---------------------------------------------------------------------------
// Transpose H: fp32 [R][C] -> HbT8 fp8 [C][R], plus straight bf16 copy [R][C]
// ---------------------------------------------------------------------------
__global__ __launch_bounds__(256) void transpose_h_kernel(
    const float* __restrict__ in, unsigned char* __restrict__ outT8,
    unsigned short* __restrict__ outN, int R, int C) {
  __shared__ float t[64][65];
  const int bc = blockIdx.x * 64;
  const int br = blockIdx.y * 64;
  const int tc = threadIdx.x & 63;
  const int tr = threadIdx.x >> 6;
  for (int r = tr; r < 64; r += 4) {
    const float v = in[(size_t)(br + r) * C + bc + tc];
    t[r][tc] = v;
    outN[(size_t)(br + r) * C + bc + tc] = f2bf(v);
  }
  __syncthreads();
  for (int r = tr; r < 64; r += 4)
    outT8[(size_t)(bc + r) * R + br + tc] = f2fp8(t[tc][r]);
}

// Transpose weights: fp32 [R][C] -> bf16 [C][R]
__global__ __launch_bounds__(256) void transpose_w_kernel(
    const float* __restrict__ in, unsigned short* __restrict__ outT, int R, int C) {
  __shared__ float t[64][65];
  const int bc = blockIdx.x * 64;
  const int br = blockIdx.y * 64;
  const int tc = threadIdx.x & 63;
  const int tr = threadIdx.x >> 6;
  for (int r = tr; r < 64; r += 4)
    t[r][tc] = in[(size_t)(br + r) * C + bc + tc];
  __syncthreads();
  for (int r = tr; r < 64; r += 4)
    outT[(size_t)(bc + r) * R + br + tc] = f2bf(t[tc][r]);
}

__global__ __launch_bounds__(256) void pack_bias_kernel(
    const float* __restrict__ bq, const float* __restrict__ bk,
    float* __restrict__ bqk) {
  int i = blockIdx.x * 256 + threadIdx.x;
  bqk[i] = (i < 512) ? bq[i] : bk[i - 512];
}

// ---------------------------------------------------------------------------
// bf16 GEMM (B-transposed), 128x128 tile, BK=32, double-buffered LDS with
// ONE barrier per k-iter: [waitvm0; barrier; stage(next); compute(cur)].
// MODE 0: C = A*B + bias -> bf16
// MODE 1: C = exp(diag0(A*B)*scale) -> fp8 e4m3, + atomic row-sums (of the
//         ROUNDED fp8 values) into lsum
// ---------------------------------------------------------------------------
template <int MODE>
__global__ __launch_bounds__(256, 4) void gemm_bt(
    const unsigned short* __restrict__ A,    // [M][lda] bf16
    const unsigned short* __restrict__ Bt,   // [Ncols][ldb] bf16
    int Ncols, int K, int lda, int ldb,
    const float* __restrict__ bias,          // MODE0
    float* __restrict__ lsum,                // MODE1
    int row0,
    unsigned short* __restrict__ Cb,         // MODE0 out
    unsigned char* __restrict__ C8)          // MODE1 out
{
  __shared__ unsigned short As[2][128 * 32];
  __shared__ unsigned short Bs[2][128 * 32];

  const int tid  = threadIdx.x;
  const int lane = tid & 63;
  const int wave = tid >> 6;
  const int wr   = (wave >> 1) * 64;
  const int wc   = (wave & 1) * 64;
  const int quad = lane >> 4;
  const int l15  = lane & 15;
  const int bm   = blockIdx.y * 128;
  const int bn   = blockIdx.x * 128;

  const int c0 = tid, c1 = tid + 256;
  const int r0a = c0 >> 2, k0a = (c0 & 3) << 3;
  const int r1a = c1 >> 2, k1a = (c1 & 3) << 3;

  auto stage = [&](int kt, int b) {
    __builtin_amdgcn_global_load_lds(
        (const GLOBAL_AS void*)(A + (size_t)(bm + r0a) * lda + kt + k0a),
        (LDS_AS void*)(&As[b][c0 * 8]), 16, 0, 0);
    __builtin_amdgcn_global_load_lds(
        (const GLOBAL_AS void*)(A + (size_t)(bm + r1a) * lda + kt + k1a),
        (LDS_AS void*)(&As[b][c1 * 8]), 16, 0, 0);
    __builtin_amdgcn_global_load_lds(
        (const GLOBAL_AS void*)(Bt + (size_t)(bn + r0a) * ldb + kt + k0a),
        (LDS_AS void*)(&Bs[b][c0 * 8]), 16, 0, 0);
    __builtin_amdgcn_global_load_lds(
        (const GLOBAL_AS void*)(Bt + (size_t)(bn + r1a) * ldb + kt + k1a),
        (LDS_AS void*)(&Bs[b][c1 * 8]), 16, 0, 0);
  };

  floatx4 acc[4][4];
#pragma unroll
  for (int i = 0; i < 4; ++i)
#pragma unroll
    for (int j = 0; j < 4; ++j)
      acc[i][j] = (floatx4){0.f, 0.f, 0.f, 0.f};

  stage(0, 0);
  const int nIter = K >> 5;
  for (int it = 0; it < nIter; ++it) {
    const int b = it & 1;
    wait_vm0();
    __syncthreads();
    if (it + 1 < nIter) stage((it + 1) << 5, b ^ 1);

    short8 af[4], bfr[4];
#pragma unroll
    for (int i = 0; i < 4; ++i)
      af[i] = *(const short8*)(&As[b][(wr + i * 16 + l15) * 32 + quad * 8]);
#pragma unroll
    for (int j = 0; j < 4; ++j)
      bfr[j] = *(const short8*)(&Bs[b][(wc + j * 16 + l15) * 32 + quad * 8]);
#pragma unroll
    for (int i = 0; i < 4; ++i)
#pragma unroll
      for (int j = 0; j < 4; ++j)
        acc[i][j] = __builtin_amdgcn_mfma_f32_16x16x32_bf16(af[i], bfr[j], acc[i][j], 0, 0, 0);
  }

  // epilogue — C/D layout: col = lane&15, row = quad*4 + reg
  const float scale = 0.044194173824159216f;  // 1/sqrt(512)
#pragma unroll
  for (int i = 0; i < 4; ++i) {
    const int rl = bm + wr + i * 16 + quad * 4;
#pragma unroll
    for (int r = 0; r < 4; ++r) {
      const int row = rl + r;
      if (MODE == 0) {
#pragma unroll
        for (int j = 0; j < 4; ++j) {
          const int col = bn + wc + j * 16 + l15;
          Cb[(size_t)row * Ncols + col] = f2bf(acc[i][j][r] + bias[col]);
        }
      } else {
        float e[4];
#pragma unroll
        for (int j = 0; j < 4; ++j) {
          const int col = bn + wc + j * 16 + l15;
          const float lg = ((row0 + row) == col) ? 0.f : acc[i][j][r] * scale;
          e[j] = fminf(__expf(lg), 448.f);
        }
        float rsum;
        const size_t rb = (size_t)row * Ncols + bn + wc + l15;
#ifdef HAVE_HW_FP8
        const int p01 = __builtin_amdgcn_cvt_pk_fp8_f32(e[0], e[1], 0, false);
        const int p23 = __builtin_amdgcn_cvt_pk_fp8_f32(e[2], e[3], 0, false);
        C8[rb]      = (unsigned char)(p01 & 0xff);
        C8[rb + 16] = (unsigned char)((p01 >> 8) & 0xff);
        C8[rb + 32] = (unsigned char)(p23 & 0xff);
        C8[rb + 48] = (unsigned char)((p23 >> 8) & 0xff);
        rsum = __builtin_amdgcn_cvt_f32_fp8(p01, 0) + __builtin_amdgcn_cvt_f32_fp8(p01, 1) +
               __builtin_amdgcn_cvt_f32_fp8(p23, 0) + __builtin_amdgcn_cvt_f32_fp8(p23, 1);
#else
        unsigned char q0 = f2fp8(e[0]), q1 = f2fp8(e[1]), q2 = f2fp8(e[2]), q3 = f2fp8(e[3]);
        C8[rb] = q0; C8[rb + 16] = q1; C8[rb + 32] = q2; C8[rb + 48] = q3;
        rsum = fp8tof(q0) + fp8tof(q1) + fp8tof(q2) + fp8tof(q3);
#endif
        rsum += __shfl_xor(rsum, 1);
        rsum += __shfl_xor(rsum, 2);
        rsum += __shfl_xor(rsum, 4);
        rsum += __shfl_xor(rsum, 8);
        if (l15 == 0) atomicAdd(&lsum[row0 + row], rsum);
      }
    }
  }
}

// ---------------------------------------------------------------------------
// PV GEMM, fp8 x fp8: O[m][n] = sum_k P8[m][k] * Bt8[n][k].
// 64x128 tile, BK=64, double-buffered (one barrier/iter), split-K over z.
// mfma_f32_16x16x32_fp8_fp8 (A/B = 8 bytes/lane as i64).
// ---------------------------------------------------------------------------
template <bool DIRECT>
__global__ __launch_bounds__(256, 4) void gemm_pv8(
    const unsigned char* __restrict__ P,     // [rows][8192] fp8 (chunk base)
    const unsigned char* __restrict__ Bt,    // HbT8 [512][8192] fp8
    int Kchunk,
    const float* __restrict__ lvec,
    const float* __restrict__ Hres,
    int row0,
    float* __restrict__ outp,                // DIRECT: out; else partials base
    size_t partStride)
{
  __shared__ unsigned char As[2][64 * 64];    // 4 KiB x2
  __shared__ unsigned char Bs[2][128 * 64];   // 8 KiB x2

  const int tid  = threadIdx.x;
  const int lane = tid & 63;
  const int wave = tid >> 6;
  const int wr   = (wave >> 1) * 32;
  const int wc   = (wave & 1) * 64;
  const int quad = lane >> 4;
  const int l15  = lane & 15;
  const int bm   = blockIdx.y * 64;
  const int bn   = blockIdx.x * 128;
  const int k0   = blockIdx.z * Kchunk;

  float* part = outp + (DIRECT ? 0 : (size_t)blockIdx.z * partStride);

  const int rA = tid >> 2,  kA = (tid & 3) << 4;    // 256 chunks: 64 rows x 64B
  const int cB1 = tid + 256;
  const int rB0 = tid >> 2, kB0 = (tid & 3) << 4;   // 512 chunks: 128 rows x 64B
  const int rB1 = cB1 >> 2, kB1 = (cB1 & 3) << 4;

  auto stage = [&](int kt, int b) {
    __builtin_amdgcn_global_load_lds(
        (const GLOBAL_AS void*)(P + (size_t)(bm + rA) * 8192 + kt + kA),
        (LDS_AS void*)(&As[b][tid * 16]), 16, 0, 0);
    __builtin_amdgcn_global_load_lds(
        (const GLOBAL_AS void*)(Bt + (size_t)(bn + rB0) * 8192 + kt + kB0),
        (LDS_AS void*)(&Bs[b][tid * 16]), 16, 0, 0);
    __builtin_amdgcn_global_load_lds(
        (const GLOBAL_AS void*)(Bt + (size_t)(bn + rB1) * 8192 + kt + kB1),
        (LDS_AS void*)(&Bs[b][cB1 * 16]), 16, 0, 0);
  };

  floatx4 acc[2][4];
#pragma unroll
  for (int i = 0; i < 2; ++i)
#pragma unroll
    for (int j = 0; j < 4; ++j)
      acc[i][j] = (floatx4){0.f, 0.f, 0.f, 0.f};

  stage(k0, 0);
  const int nIter = Kchunk >> 6;
  for (int it = 0; it < nIter; ++it) {
    const int b = it & 1;
    wait_vm0();
    __syncthreads();
    if (it + 1 < nIter) stage(k0 + ((it + 1) << 6), b ^ 1);

#pragma unroll
    for (int kk = 0; kk < 2; ++kk) {
      long af[2], bfr[4];
#pragma unroll
      for (int i = 0; i < 2; ++i)
        af[i] = *(const long*)(&As[b][(wr + i * 16 + l15) * 64 + kk * 32 + quad * 8]);
#pragma unroll
      for (int j = 0; j < 4; ++j)
        bfr[j] = *(const long*)(&Bs[b][(wc + j * 16 + l15) * 64 + kk * 32 + quad * 8]);
#pragma unroll
      for (int i = 0; i < 2; ++i)
#pragma unroll
        for (int j = 0; j < 4; ++j)
          acc[i][j] = __builtin_amdgcn_mfma_f32_16x16x32_fp8_fp8(af[i], bfr[j], acc[i][j], 0, 0, 0);
    }
  }

#pragma unroll
  for (int i = 0; i < 2; ++i) {
    const int rl = bm + wr + i * 16 + quad * 4;
#pragma unroll
    for (int j = 0; j < 4; ++j) {
      const int col = bn + wc + j * 16 + l15;
#pragma unroll
      for (int r = 0; r < 4; ++r) {
        const int row = rl + r;
        const float v = acc[i][j][r];
        if (DIRECT) {
          const int grow = row0 + row;
          part[(size_t)grow * 512 + col] =
              v / lvec[grow] + Hres[(size_t)grow * 512 + col];
        } else {
          part[(size_t)row * 512 + col] = v;
        }
      }
    }
  }
}

// combine (S=2): out = (p0 + p1) / l[row] + H
__global__ __launch_bounds__(256) void combine_kernel(
    const float* __restrict__ parts, size_t partStride,
    const float* __restrict__ lvec, const float* __restrict__ Hres,
    float* __restrict__ out, int n4) {
  int i = blockIdx.x * 256 + threadIdx.x;
  if (i >= n4) return;
  float4 a = ((const float4*)parts)[i];
  const float4 b = ((const float4*)(parts + partStride))[i];
  const int row = i >> 7;
  const float inv = 1.f / lvec[row];
  const float4 h = ((const float4*)Hres)[i];
  float4 o;
  o.x = (a.x + b.x) * inv + h.x;
  o.y = (a.y + b.y) * inv + h.y;
  o.z = (a.z + b.z) * inv + h.z;
  o.w = (a.w + b.w) * inv + h.w;
  ((float4*)out)[i] = o;
}

// ---------------------------------------------------------------------------
extern "C" void kernel_launch(void* const* d_in, const int* in_sizes, int n_in,
                              void* d_out, int out_size, void* d_ws, size_t ws_size,
                              hipStream_t stream) {
  const float* H  = (const float*)d_in[0];
  const float* Wq = (const float*)d_in[1];
  const float* bq = (const float*)d_in[2];
  const float* Wk = (const float*)d_in[3];
  const float* bk = (const float*)d_in[4];
  float* out = (float*)d_out;

  const int N = 8192, D = 512;

  char* ws = (char*)d_ws;
  size_t off = 0;
  auto alloc = [&](size_t bytes) { char* p = ws + off; off += bytes; return p; };
  unsigned short* Hb   = (unsigned short*)alloc((size_t)N * D * 2);       // 8 MB
  unsigned char*  HbT8 = (unsigned char*)alloc((size_t)D * N);            // 4.2 MB
  unsigned short* QKb  = (unsigned short*)alloc((size_t)N * 2 * D * 2);   // 16.8 MB
  unsigned short* BqkT = (unsigned short*)alloc((size_t)2 * D * D * 2);   // 1 MB
  float* bqk = (float*)alloc((size_t)2 * D * 4);
  float* l   = (float*)alloc((size_t)N * 4);
  const size_t base = off;
  unsigned char* P8 = (unsigned char*)(ws + base);

  const size_t pBytes = (size_t)N * N;                   // 67 MB (fp8)
  const size_t partBytes = (size_t)N * D * 4;            // 16.8 MB each
  const size_t partStride = (size_t)N * D;               // floats
  const size_t avail = (ws_size > base) ? (ws_size - base) : 0;

  int S = 0;
  if (avail >= pBytes) S = (avail - pBytes >= 2 * partBytes) ? 2 : 1;
  float* parts = (float*)(ws + base + pBytes);

  // --- prep ---
  hipMemsetAsync(l, 0, (size_t)N * 4, stream);
  transpose_h_kernel<<<dim3(D / 64, N / 64), 256, 0, stream>>>(H, HbT8, Hb, N, D);
  transpose_w_kernel<<<dim3(D / 64, D / 64), 256, 0, stream>>>(Wq, BqkT, D, D);
  transpose_w_kernel<<<dim3(D / 64, D / 64), 256, 0, stream>>>(Wk, BqkT + (size_t)D * D, D, D);
  pack_bias_kernel<<<dim3(4), 256, 0, stream>>>(bq, bk, bqk);

  // --- merged Q|K projection: QKb[8192][1024] = Hb @ [Wq|Wk] + [bq|bk] ---
  gemm_bt<0><<<dim3(2 * D / 128, N / 128), 256, 0, stream>>>(
      Hb, BqkT, 2 * D, D, D, D, bqk, nullptr, 0, QKb, nullptr);

  if (S >= 1) {
    // scores: P8 = fp8(exp(diag0(Q K^T)*scale)), fused row-sums into l
    gemm_bt<1><<<dim3(N / 128, N / 128), 256, 0, stream>>>(
        QKb, QKb + D, N, D, 2 * D, 2 * D, nullptr, l, 0, nullptr, P8);
    if (S == 1) {
      gemm_pv8<true><<<dim3(D / 128, N / 64, 1), 256, 0, stream>>>(
          P8, HbT8, N, l, H, 0, out, 0);
    } else {
      gemm_pv8<false><<<dim3(D / 128, N / 64, 2), 256, 0, stream>>>(
          P8, HbT8, N / 2, nullptr, nullptr, 0, parts, partStride);
      combine_kernel<<<dim3((N * D / 4 + 255) / 256), 256, 0, stream>>>(
          parts, partStride, l, H, out, N * D / 4);
    }
  } else {
    // ws too small for full P8: chunk rows (direct PV per chunk)
    int maxRows = (int)(avail / (size_t)N);
    maxRows &= ~127;
    if (maxRows < 128) maxRows = 128;
    for (int r0 = 0; r0 < N; r0 += maxRows) {
      int rows = N - r0;
      if (rows > maxRows) rows = maxRows;
      gemm_bt<1><<<dim3(N / 128, rows / 128), 256, 0, stream>>>(
          QKb + (size_t)r0 * 2 * D, QKb + D, N, D, 2 * D, 2 * D, nullptr, l, r0, nullptr, P8);
      gemm_pv8<true><<<dim3(D / 128, rows / 64, 1), 256, 0, stream>>>(
          P8, HbT8, N, l, H, r0, out, 0);
    }
  }
}

// Round 5
// 287.418 us; speedup vs baseline: 1.4283x; 1.4283x over previous
//
#include <hip/hip_runtime.h>
#include <cstdint>
#include <cstddef>

#define GLOBAL_AS __attribute__((address_space(1)))
#define LDS_AS __attribute__((address_space(3)))

typedef __attribute__((ext_vector_type(8))) short short8;
typedef __attribute__((ext_vector_type(4))) float floatx4;
typedef __attribute__((ext_vector_type(2))) long long2v;   // 16B LDS read

#if defined(__has_builtin)
#if __has_builtin(__builtin_amdgcn_cvt_pk_fp8_f32) && __has_builtin(__builtin_amdgcn_cvt_f32_fp8)
#define HAVE_HW_FP8 1
#endif
#endif

static __device__ __forceinline__ unsigned short f2bf(float f) {
  uint32_t u = __builtin_bit_cast(uint32_t, f);
  u += 0x7fffu + ((u >> 16) & 1u);
  return (unsigned short)(u >> 16);
}

// OCP e4m3 encode (RNE, saturate to 448)
static __device__ __forceinline__ unsigned char f2fp8(float f) {
#ifdef HAVE_HW_FP8
  float c = fminf(fmaxf(f, -448.f), 448.f);
  return (unsigned char)(__builtin_amdgcn_cvt_pk_fp8_f32(c, 0.f, 0, false) & 0xff);
#else
  unsigned char s = 0;
  if (f < 0.f) { s = 0x80; f = -f; }
  if (f >= 448.f) return s | 0x7e;
  if (f < 0.015625f) { int r = (int)(f * 512.f + 0.5f); return s | (unsigned char)r; }
  uint32_t u = __builtin_bit_cast(uint32_t, f);
  int e = (int)((u >> 23) & 0xff) - 127;
  uint32_t keep = (u >> 20) & 7, rest = u & 0xfffffu;
  if (rest > 0x80000u || (rest == 0x80000u && (keep & 1))) ++keep;
  if (keep == 8) { keep = 0; ++e; }
  if (e > 8) return s | 0x7e;
  return s | (unsigned char)(((e + 7) << 3) | keep);
#endif
}
#ifndef HAVE_HW_FP8
static __device__ __forceinline__ float fp8tof(unsigned int b) {
  float sg = (b & 0x80) ? -1.f : 1.f;
  int e = (b >> 3) & 0xf, m = b & 7;
  if (e == 0) return sg * (float)m * 0.001953125f;
  return sg * (1.f + (float)m * 0.125f) * exp2f((float)(e - 7));
}
#endif

static __device__ __forceinline__ void wait_vm0() {
  // vmcnt(0), expcnt/lgkmcnt unconstrained
  __builtin_amdgcn_s_waitcnt(0x0f70);
}

// ---------------------------------------------------------------------------
// Transpose H: fp32 [R][C] -> HbT8 fp8 [C][R], plus straight bf16 copy [R][C]
// ---------------------------------------------------------------------------
__global__ __launch_bounds__(256) void transpose_h_kernel(
    const float* __restrict__ in, unsigned char* __restrict__ outT8,
    unsigned short* __restrict__ outN, int R, int C) {
  __shared__ float t[64][65];
  const int bc = blockIdx.x * 64;
  const int br = blockIdx.y * 64;
  const int tc = threadIdx.x & 63;
  const int tr = threadIdx.x >> 6;
  for (int r = tr; r < 64; r += 4) {
    const float v = in[(size_t)(br + r) * C + bc + tc];
    t[r][tc] = v;
    outN[(size_t)(br + r) * C + bc + tc] = f2bf(v);
  }
  __syncthreads();
  for (int r = tr; r < 64; r += 4)
    outT8[(size_t)(bc + r) * R + br + tc] = f2fp8(t[tc][r]);
}

// Transpose weights: fp32 [R][C] -> bf16 [C][R]
__global__ __launch_bounds__(256) void transpose_w_kernel(
    const float* __restrict__ in, unsigned short* __restrict__ outT, int R, int C) {
  __shared__ float t[64][65];
  const int bc = blockIdx.x * 64;
  const int br = blockIdx.y * 64;
  const int tc = threadIdx.x & 63;
  const int tr = threadIdx.x >> 6;
  for (int r = tr; r < 64; r += 4)
    t[r][tc] = in[(size_t)(br + r) * C + bc + tc];
  __syncthreads();
  for (int r = tr; r < 64; r += 4)
    outT[(size_t)(bc + r) * R + br + tc] = f2bf(t[tc][r]);
}

__global__ __launch_bounds__(256) void pack_bias_kernel(
    const float* __restrict__ bq, const float* __restrict__ bk,
    float* __restrict__ bqk) {
  int i = blockIdx.x * 256 + threadIdx.x;
  bqk[i] = (i < 512) ? bq[i] : bk[i - 512];
}

// ---------------------------------------------------------------------------
// Projection GEMM (bf16 x bf16 -> fp8): QK8[m][n] = fp8(A[m][k]*Bt[n][k]+b[n])
// 128x128 tile, BK=32, double-buffered one-barrier K-loop.
// ---------------------------------------------------------------------------
__global__ __launch_bounds__(256, 4) void gemm_proj(
    const unsigned short* __restrict__ A,    // Hb [8192][512] bf16
    const unsigned short* __restrict__ Bt,   // BqkT [1024][512] bf16
    int Ncols, int K,
    const float* __restrict__ bias,
    unsigned char* __restrict__ C8)          // QK8 [8192][1024] fp8
{
  __shared__ unsigned short As[2][128 * 32];
  __shared__ unsigned short Bs[2][128 * 32];

  const int tid  = threadIdx.x;
  const int lane = tid & 63;
  const int wave = tid >> 6;
  const int wr   = (wave >> 1) * 64;
  const int wc   = (wave & 1) * 64;
  const int quad = lane >> 4;
  const int l15  = lane & 15;
  const int bm   = blockIdx.y * 128;
  const int bn   = blockIdx.x * 128;

  const int c0 = tid, c1 = tid + 256;
  const int r0a = c0 >> 2, k0a = (c0 & 3) << 3;
  const int r1a = c1 >> 2, k1a = (c1 & 3) << 3;

  auto stage = [&](int kt, int b) {
    __builtin_amdgcn_global_load_lds(
        (const GLOBAL_AS void*)(A + (size_t)(bm + r0a) * K + kt + k0a),
        (LDS_AS void*)(&As[b][c0 * 8]), 16, 0, 0);
    __builtin_amdgcn_global_load_lds(
        (const GLOBAL_AS void*)(A + (size_t)(bm + r1a) * K + kt + k1a),
        (LDS_AS void*)(&As[b][c1 * 8]), 16, 0, 0);
    __builtin_amdgcn_global_load_lds(
        (const GLOBAL_AS void*)(Bt + (size_t)(bn + r0a) * K + kt + k0a),
        (LDS_AS void*)(&Bs[b][c0 * 8]), 16, 0, 0);
    __builtin_amdgcn_global_load_lds(
        (const GLOBAL_AS void*)(Bt + (size_t)(bn + r1a) * K + kt + k1a),
        (LDS_AS void*)(&Bs[b][c1 * 8]), 16, 0, 0);
  };

  floatx4 acc[4][4];
#pragma unroll
  for (int i = 0; i < 4; ++i)
#pragma unroll
    for (int j = 0; j < 4; ++j)
      acc[i][j] = (floatx4){0.f, 0.f, 0.f, 0.f};

  stage(0, 0);
  const int nIter = K >> 5;
  for (int it = 0; it < nIter; ++it) {
    const int b = it & 1;
    wait_vm0();
    __syncthreads();
    if (it + 1 < nIter) stage((it + 1) << 5, b ^ 1);

    short8 af[4], bfr[4];
#pragma unroll
    for (int i = 0; i < 4; ++i)
      af[i] = *(const short8*)(&As[b][(wr + i * 16 + l15) * 32 + quad * 8]);
#pragma unroll
    for (int j = 0; j < 4; ++j)
      bfr[j] = *(const short8*)(&Bs[b][(wc + j * 16 + l15) * 32 + quad * 8]);
#pragma unroll
    for (int i = 0; i < 4; ++i)
#pragma unroll
      for (int j = 0; j < 4; ++j)
        acc[i][j] = __builtin_amdgcn_mfma_f32_16x16x32_bf16(af[i], bfr[j], acc[i][j], 0, 0, 0);
  }

  // epilogue — C/D layout: col = lane&15, row = quad*4 + reg
#pragma unroll
  for (int i = 0; i < 4; ++i) {
    const int rl = bm + wr + i * 16 + quad * 4;
#pragma unroll
    for (int r = 0; r < 4; ++r) {
      const int row = rl + r;
#pragma unroll
      for (int j = 0; j < 4; ++j) {
        const int col = bn + wc + j * 16 + l15;
        C8[(size_t)row * Ncols + col] = f2fp8(acc[i][j][r] + bias[col]);
      }
    }
  }
}

// ---------------------------------------------------------------------------
// Scores GEMM fp8 x fp8: P8 = fp8(exp(diag0(Q K^T)*scale)), fused row-sums.
// 128x128 tile, BK=64, double-buffered one-barrier loop.
// K-permutation trick: mfma call t, quad q covers global k = q*16 + t*8 + j,
// so each lane's two 8B fragments are one contiguous 16B ds_read_b128 at
// row*64 + quad*16 (bank pattern identical to the proven bf16 layout).
// ---------------------------------------------------------------------------
__global__ __launch_bounds__(256, 4) void gemm_qk8(
    const unsigned char* __restrict__ A,     // Q8 rows [.][lda] fp8
    const unsigned char* __restrict__ Bt,    // K8 [8192][ldb] fp8
    int Ncols, int K, int lda, int ldb,
    float* __restrict__ lsum,
    int row0,
    unsigned char* __restrict__ P8)
{
  __shared__ unsigned char As[2][128 * 64];   // 8 KiB x2
  __shared__ unsigned char Bs[2][128 * 64];   // 8 KiB x2

  const int tid  = threadIdx.x;
  const int lane = tid & 63;
  const int wave = tid >> 6;
  const int wr   = (wave >> 1) * 64;
  const int wc   = (wave & 1) * 64;
  const int quad = lane >> 4;
  const int l15  = lane & 15;
  const int bm   = blockIdx.y * 128;
  const int bn   = blockIdx.x * 128;

  // staging: 512 chunks of 16B cover 128 rows x 64B; c -> row c>>2, kofs (c&3)*16
  const int c0 = tid, c1 = tid + 256;
  const int r0a = c0 >> 2, k0a = (c0 & 3) << 4;
  const int r1a = c1 >> 2, k1a = (c1 & 3) << 4;

  auto stage = [&](int kt, int b) {
    __builtin_amdgcn_global_load_lds(
        (const GLOBAL_AS void*)(A + (size_t)(bm + r0a) * lda + kt + k0a),
        (LDS_AS void*)(&As[b][c0 * 16]), 16, 0, 0);
    __builtin_amdgcn_global_load_lds(
        (const GLOBAL_AS void*)(A + (size_t)(bm + r1a) * lda + kt + k1a),
        (LDS_AS void*)(&As[b][c1 * 16]), 16, 0, 0);
    __builtin_amdgcn_global_load_lds(
        (const GLOBAL_AS void*)(Bt + (size_t)(bn + r0a) * ldb + kt + k0a),
        (LDS_AS void*)(&Bs[b][c0 * 16]), 16, 0, 0);
    __builtin_amdgcn_global_load_lds(
        (const GLOBAL_AS void*)(Bt + (size_t)(bn + r1a) * ldb + kt + k1a),
        (LDS_AS void*)(&Bs[b][c1 * 16]), 16, 0, 0);
  };

  floatx4 acc[4][4];
#pragma unroll
  for (int i = 0; i < 4; ++i)
#pragma unroll
    for (int j = 0; j < 4; ++j)
      acc[i][j] = (floatx4){0.f, 0.f, 0.f, 0.f};

  stage(0, 0);
  const int nIter = K >> 6;
  for (int it = 0; it < nIter; ++it) {
    const int b = it & 1;
    wait_vm0();
    __syncthreads();
    if (it + 1 < nIter) stage((it + 1) << 6, b ^ 1);

    long2v af[4], bfr[4];
#pragma unroll
    for (int i = 0; i < 4; ++i)
      af[i] = *(const long2v*)(&As[b][(wr + i * 16 + l15) * 64 + quad * 16]);
#pragma unroll
    for (int j = 0; j < 4; ++j)
      bfr[j] = *(const long2v*)(&Bs[b][(wc + j * 16 + l15) * 64 + quad * 16]);
#pragma unroll
    for (int i = 0; i < 4; ++i)
#pragma unroll
      for (int j = 0; j < 4; ++j) {
        acc[i][j] = __builtin_amdgcn_mfma_f32_16x16x32_fp8_fp8(af[i].x, bfr[j].x, acc[i][j], 0, 0, 0);
        acc[i][j] = __builtin_amdgcn_mfma_f32_16x16x32_fp8_fp8(af[i].y, bfr[j].y, acc[i][j], 0, 0, 0);
      }
  }

  const float scale = 0.044194173824159216f;  // 1/sqrt(512)
#pragma unroll
  for (int i = 0; i < 4; ++i) {
    const int rl = bm + wr + i * 16 + quad * 4;
#pragma unroll
    for (int r = 0; r < 4; ++r) {
      const int row = rl + r;
      float e[4];
#pragma unroll
      for (int j = 0; j < 4; ++j) {
        const int col = bn + wc + j * 16 + l15;
        const float lg = ((row0 + row) == col) ? 0.f : acc[i][j][r] * scale;
        e[j] = fminf(__expf(lg), 448.f);
      }
      float rsum;
      const size_t rb = (size_t)row * Ncols + bn + wc + l15;
#ifdef HAVE_HW_FP8
      const int p01 = __builtin_amdgcn_cvt_pk_fp8_f32(e[0], e[1], 0, false);
      const int p23 = __builtin_amdgcn_cvt_pk_fp8_f32(e[2], e[3], 0, false);
      P8[rb]      = (unsigned char)(p01 & 0xff);
      P8[rb + 16] = (unsigned char)((p01 >> 8) & 0xff);
      P8[rb + 32] = (unsigned char)(p23 & 0xff);
      P8[rb + 48] = (unsigned char)((p23 >> 8) & 0xff);
      rsum = __builtin_amdgcn_cvt_f32_fp8(p01, 0) + __builtin_amdgcn_cvt_f32_fp8(p01, 1) +
             __builtin_amdgcn_cvt_f32_fp8(p23, 0) + __builtin_amdgcn_cvt_f32_fp8(p23, 1);
#else
      unsigned char q0 = f2fp8(e[0]), q1 = f2fp8(e[1]), q2 = f2fp8(e[2]), q3 = f2fp8(e[3]);
      P8[rb] = q0; P8[rb + 16] = q1; P8[rb + 32] = q2; P8[rb + 48] = q3;
      rsum = fp8tof(q0) + fp8tof(q1) + fp8tof(q2) + fp8tof(q3);
#endif
      rsum += __shfl_xor(rsum, 1);
      rsum += __shfl_xor(rsum, 2);
      rsum += __shfl_xor(rsum, 4);
      rsum += __shfl_xor(rsum, 8);
      if (l15 == 0) atomicAdd(&lsum[row0 + row], rsum);
    }
  }
}

// ---------------------------------------------------------------------------
// PV GEMM fp8 x fp8: O[m][n] = sum_k P8[m][k]*HbT8[n][k]. 64x128 tile, BK=64,
// double-buffered, split-K over z. Same K-permutation b128 trick as gemm_qk8.
// ---------------------------------------------------------------------------
template <bool DIRECT>
__global__ __launch_bounds__(256, 4) void gemm_pv8(
    const unsigned char* __restrict__ P,     // [rows][8192] fp8 (chunk base)
    const unsigned char* __restrict__ Bt,    // HbT8 [512][8192] fp8
    int Kchunk,
    const float* __restrict__ lvec,
    const float* __restrict__ Hres,
    int row0,
    float* __restrict__ outp,
    size_t partStride)
{
  __shared__ unsigned char As[2][64 * 64];    // 4 KiB x2
  __shared__ unsigned char Bs[2][128 * 64];   // 8 KiB x2

  const int tid  = threadIdx.x;
  const int lane = tid & 63;
  const int wave = tid >> 6;
  const int wr   = (wave >> 1) * 32;
  const int wc   = (wave & 1) * 64;
  const int quad = lane >> 4;
  const int l15  = lane & 15;
  const int bm   = blockIdx.y * 64;
  const int bn   = blockIdx.x * 128;
  const int k0   = blockIdx.z * Kchunk;

  float* part = outp + (DIRECT ? 0 : (size_t)blockIdx.z * partStride);

  const int rA = tid >> 2,  kA = (tid & 3) << 4;    // 256 chunks: 64 rows x 64B
  const int cB1 = tid + 256;
  const int rB0 = tid >> 2, kB0 = (tid & 3) << 4;   // 512 chunks: 128 rows x 64B
  const int rB1 = cB1 >> 2, kB1 = (cB1 & 3) << 4;

  auto stage = [&](int kt, int b) {
    __builtin_amdgcn_global_load_lds(
        (const GLOBAL_AS void*)(P + (size_t)(bm + rA) * 8192 + kt + kA),
        (LDS_AS void*)(&As[b][tid * 16]), 16, 0, 0);
    __builtin_amdgcn_global_load_lds(
        (const GLOBAL_AS void*)(Bt + (size_t)(bn + rB0) * 8192 + kt + kB0),
        (LDS_AS void*)(&Bs[b][tid * 16]), 16, 0, 0);
    __builtin_amdgcn_global_load_lds(
        (const GLOBAL_AS void*)(Bt + (size_t)(bn + rB1) * 8192 + kt + kB1),
        (LDS_AS void*)(&Bs[b][cB1 * 16]), 16, 0, 0);
  };

  floatx4 acc[2][4];
#pragma unroll
  for (int i = 0; i < 2; ++i)
#pragma unroll
    for (int j = 0; j < 4; ++j)
      acc[i][j] = (floatx4){0.f, 0.f, 0.f, 0.f};

  stage(k0, 0);
  const int nIter = Kchunk >> 6;
  for (int it = 0; it < nIter; ++it) {
    const int b = it & 1;
    wait_vm0();
    __syncthreads();
    if (it + 1 < nIter) stage(k0 + ((it + 1) << 6), b ^ 1);

    long2v af[2], bfr[4];
#pragma unroll
    for (int i = 0; i < 2; ++i)
      af[i] = *(const long2v*)(&As[b][(wr + i * 16 + l15) * 64 + quad * 16]);
#pragma unroll
    for (int j = 0; j < 4; ++j)
      bfr[j] = *(const long2v*)(&Bs[b][(wc + j * 16 + l15) * 64 + quad * 16]);
#pragma unroll
    for (int i = 0; i < 2; ++i)
#pragma unroll
      for (int j = 0; j < 4; ++j) {
        acc[i][j] = __builtin_amdgcn_mfma_f32_16x16x32_fp8_fp8(af[i].x, bfr[j].x, acc[i][j], 0, 0, 0);
        acc[i][j] = __builtin_amdgcn_mfma_f32_16x16x32_fp8_fp8(af[i].y, bfr[j].y, acc[i][j], 0, 0, 0);
      }
  }

#pragma unroll
  for (int i = 0; i < 2; ++i) {
    const int rl = bm + wr + i * 16 + quad * 4;
#pragma unroll
    for (int j = 0; j < 4; ++j) {
      const int col = bn + wc + j * 16 + l15;
#pragma unroll
      for (int r = 0; r < 4; ++r) {
        const int row = rl + r;
        const float v = acc[i][j][r];
        if (DIRECT) {
          const int grow = row0 + row;
          part[(size_t)grow * 512 + col] =
              v / lvec[grow] + Hres[(size_t)grow * 512 + col];
        } else {
          part[(size_t)row * 512 + col] = v;
        }
      }
    }
  }
}

// combine: out = (sum_s partial_s) / l[row] + H
__global__ __launch_bounds__(256) void combine_kernel(
    const float* __restrict__ parts, size_t partStride, int S,
    const float* __restrict__ lvec, const float* __restrict__ Hres,
    float* __restrict__ out, int n4) {
  int i = blockIdx.x * 256 + threadIdx.x;
  if (i >= n4) return;
  float4 a = ((const float4*)parts)[i];
  for (int s = 1; s < S; ++s) {
    const float4 b = ((const float4*)(parts + (size_t)s * partStride))[i];
    a.x += b.x; a.y += b.y; a.z += b.z; a.w += b.w;
  }
  const int row = i >> 7;
  const float inv = 1.f / lvec[row];
  const float4 h = ((const float4*)Hres)[i];
  float4 o;
  o.x = a.x * inv + h.x;
  o.y = a.y * inv + h.y;
  o.z = a.z * inv + h.z;
  o.w = a.w * inv + h.w;
  ((float4*)out)[i] = o;
}

// ---------------------------------------------------------------------------
extern "C" void kernel_launch(void* const* d_in, const int* in_sizes, int n_in,
                              void* d_out, int out_size, void* d_ws, size_t ws_size,
                              hipStream_t stream) {
  const float* H  = (const float*)d_in[0];
  const float* Wq = (const float*)d_in[1];
  const float* bq = (const float*)d_in[2];
  const float* Wk = (const float*)d_in[3];
  const float* bk = (const float*)d_in[4];
  float* out = (float*)d_out;

  const int N = 8192, D = 512;

  char* ws = (char*)d_ws;
  size_t off = 0;
  auto alloc = [&](size_t bytes) { char* p = ws + off; off += bytes; return p; };
  unsigned short* Hb   = (unsigned short*)alloc((size_t)N * D * 2);       // 8 MB
  unsigned char*  HbT8 = (unsigned char*)alloc((size_t)D * N);            // 4.2 MB
  unsigned char*  QK8  = (unsigned char*)alloc((size_t)N * 2 * D);        // 8.4 MB
  unsigned short* BqkT = (unsigned short*)alloc((size_t)2 * D * D * 2);   // 1 MB
  float* bqk = (float*)alloc((size_t)2 * D * 4);
  float* l   = (float*)alloc((size_t)N * 4);
  const size_t base = off;
  unsigned char* P8 = (unsigned char*)(ws + base);

  const size_t pBytes = (size_t)N * N;                   // 67 MB (fp8)
  const size_t partBytes = (size_t)N * D * 4;            // 16.8 MB each
  const size_t partStride = (size_t)N * D;               // floats
  const size_t avail = (ws_size > base) ? (ws_size - base) : 0;

  int S = 0;
  if (avail >= pBytes) {
    const size_t extra = avail - pBytes;
    S = (extra >= 4 * partBytes) ? 4 : (extra >= 2 * partBytes) ? 2 : 1;
  }
  float* parts = (float*)(ws + base + pBytes);

  // --- prep ---
  hipMemsetAsync(l, 0, (size_t)N * 4, stream);
  transpose_h_kernel<<<dim3(D / 64, N / 64), 256, 0, stream>>>(H, HbT8, Hb, N, D);
  transpose_w_kernel<<<dim3(D / 64, D / 64), 256, 0, stream>>>(Wq, BqkT, D, D);
  transpose_w_kernel<<<dim3(D / 64, D / 64), 256, 0, stream>>>(Wk, BqkT + (size_t)D * D, D, D);
  pack_bias_kernel<<<dim3(4), 256, 0, stream>>>(bq, bk, bqk);

  // --- merged Q|K projection -> fp8: QK8[8192][1024] ---
  gemm_proj<<<dim3(2 * D / 128, N / 128), 256, 0, stream>>>(
      Hb, BqkT, 2 * D, D, bqk, QK8);

  if (S >= 1) {
    // scores: P8 = fp8(exp(diag0(Q K^T)*scale)), fused row-sums into l
    gemm_qk8<<<dim3(N / 128, N / 128), 256, 0, stream>>>(
        QK8, QK8 + D, N, D, 2 * D, 2 * D, l, 0, P8);
    if (S == 1) {
      gemm_pv8<true><<<dim3(D / 128, N / 64, 1), 256, 0, stream>>>(
          P8, HbT8, N, l, H, 0, out, 0);
    } else {
      gemm_pv8<false><<<dim3(D / 128, N / 64, S), 256, 0, stream>>>(
          P8, HbT8, N / S, nullptr, nullptr, 0, parts, partStride);
      combine_kernel<<<dim3((N * D / 4 + 255) / 256), 256, 0, stream>>>(
          parts, partStride, S, l, H, out, N * D / 4);
    }
  } else {
    // ws too small for full P8: chunk rows (direct PV per chunk)
    int maxRows = (int)(avail / (size_t)N);
    maxRows &= ~127;
    if (maxRows < 128) maxRows = 128;
    for (int r0 = 0; r0 < N; r0 += maxRows) {
      int rows = N - r0;
      if (rows > maxRows) rows = maxRows;
      gemm_qk8<<<dim3(N / 128, rows / 128), 256, 0, stream>>>(
          QK8 + (size_t)r0 * 2 * D, QK8 + D, N, D, 2 * D, 2 * D, l, r0, P8);
      gemm_pv8<true><<<dim3(D / 128, rows / 64, 1), 256, 0, stream>>>(
          P8, HbT8, N, l, H, r0, out, 0);
    }
  }
}